// Round 3
// baseline (273.790 us; speedup 1.0000x reference)
//
#include <hip/hip_runtime.h>
#include <hip/hip_bf16.h>

#define N_CL   50000
#define FEAT   64
#define HID    256
#define KD     256
#define T_SEL  1000
#define NBLK   782                 // ceil(50000/64) clause groups
#define ECHUNK 6250                // int4s per half-event (N_CL/4/2)
#define EFULL  24                  // full 256-wide iterations (24*256=6144)

// ws layout (in floats)
#define WK_OFF  0                          // 256*2 folded weights
#define CK_OFF  512                        // 2 bias constants
#define MQ_OFF  514                        // 2 uint max-keys
#define LG_OFF  520                        // 2*N_CL final logits (16B aligned)
#define ACC_OFF (LG_OFF + 2 * N_CL)        // T_SEL*8: per (t,half) s,sg,np,ng

__device__ __forceinline__ unsigned fkey(float f) {
    unsigned u = __float_as_uint(f);
    return (u & 0x80000000u) ? ~u : (u | 0x80000000u);   // monotone float->uint
}
__device__ __forceinline__ float finv(unsigned k) {
    unsigned u = (k & 0x80000000u) ? (k ^ 0x80000000u) : ~k;
    return __uint_as_float(u);
}

// ---------------------------------------------------------------- kernel A
// Wk[j][q] = dot(W2 row j, keys_W row q); ck[q] = dot(keys_W[q], b2).
__global__ __launch_bounds__(256) void prep_kernel(
        const float* __restrict__ W2, const float* __restrict__ b2,
        const float* __restrict__ keysW,
        float* __restrict__ wk, float* __restrict__ ck,
        unsigned* __restrict__ mq) {
    __shared__ float sk0[KD], sk1[KD], sb2[KD], red[256];
    int tid = threadIdx.x;
    sk0[tid] = keysW[tid];
    sk1[tid] = keysW[KD + tid];
    sb2[tid] = b2[tid];
    if (tid < 2) mq[tid] = 0u;
    __syncthreads();

    const float* w2r = W2 + (size_t)tid * KD;
    float a0 = 0.f, a1 = 0.f;
    #pragma unroll 4
    for (int k = 0; k < KD; k++) {
        float w = w2r[k];
        a0 = fmaf(w, sk0[k], a0);
        a1 = fmaf(w, sk1[k], a1);
    }
    wk[tid * 2 + 0] = a0;
    wk[tid * 2 + 1] = a1;

    red[tid] = sk0[tid] * sb2[tid];
    __syncthreads();
    for (int s = 128; s > 0; s >>= 1) { if (tid < s) red[tid] += red[tid + s]; __syncthreads(); }
    if (tid == 0) ck[0] = red[0];
    __syncthreads();
    red[tid] = sk1[tid] * sb2[tid];
    __syncthreads();
    for (int s = 128; s > 0; s >>= 1) { if (tid < s) red[tid] += red[tid + s]; __syncthreads(); }
    if (tid == 0) ck[1] = red[0];
}

// ---------------------------------------------------------------- kernel B
// Fused MLP + logits finalize. 256 threads = 4 waves; wave w computes the
// partial logit over hidden units [w*64, w*64+64) for 64 clauses; LDS reduce
// across waves; wave 0 writes final logits and does the block max -> atomicMax.
__global__ __launch_bounds__(256) void mlp_kernel(
        const float* __restrict__ X, const float* __restrict__ W1,
        const float* __restrict__ b1, const float* __restrict__ wk,
        const float* __restrict__ ck, float* __restrict__ lg,
        unsigned* __restrict__ mq) {
    int lane = threadIdx.x & 63;
    int w    = threadIdx.x >> 6;
    int n    = blockIdx.x * 64 + lane;
    int nc   = (n < N_CL) ? n : (N_CL - 1);

    float x[FEAT];
    const float4* xp = (const float4*)(X + (size_t)nc * FEAT);
    #pragma unroll
    for (int k4 = 0; k4 < FEAT / 4; k4++) {
        float4 v = xp[k4];
        x[4 * k4 + 0] = v.x; x[4 * k4 + 1] = v.y;
        x[4 * k4 + 2] = v.z; x[4 * k4 + 3] = v.w;
    }

    int j0 = w * 64;
    float l0 = 0.f, l1 = 0.f;
    for (int jg = 0; jg < 64; jg += 16) {
        float h[16];
        #pragma unroll
        for (int u = 0; u < 16; u++) h[u] = b1[j0 + jg + u];
        #pragma unroll 4
        for (int k = 0; k < FEAT; k++) {
            const float* w1r = W1 + (size_t)k * HID + j0 + jg;
            float xv = x[k];
            #pragma unroll
            for (int u = 0; u < 16; u++) h[u] = fmaf(xv, w1r[u], h[u]);
        }
        #pragma unroll
        for (int u = 0; u < 16; u++) {
            float hv = fmaxf(h[u], 0.0f);
            l0 = fmaf(hv, wk[(j0 + jg + u) * 2 + 0], l0);
            l1 = fmaf(hv, wk[(j0 + jg + u) * 2 + 1], l1);
        }
    }

    __shared__ float red[4][2][64];
    red[w][0][lane] = l0;
    red[w][1][lane] = l1;
    __syncthreads();
    if (w == 0) {
        float a0 = red[0][0][lane] + red[1][0][lane] + red[2][0][lane] + red[3][0][lane] + ck[0];
        float a1 = red[0][1][lane] + red[1][1][lane] + red[2][1][lane] + red[3][1][lane] + ck[1];
        float m0 = -1e30f, m1 = -1e30f;
        if (n < N_CL) {
            lg[n]        = a0;
            lg[N_CL + n] = a1;
            m0 = a0; m1 = a1;
        }
        for (int off = 32; off; off >>= 1) {
            m0 = fmaxf(m0, __shfl_xor(m0, off));
            m1 = fmaxf(m1, __shfl_xor(m1, off));
        }
        if (lane == 0) {
            atomicMax(mq + 0, fkey(m0));
            atomicMax(mq + 1, fkey(m1));
        }
    }
}

// ---------------------------------------------------------------- kernel D
// Streaming pass over the int32 masks. Grid = T_SEL*2 (event x half); each
// thread runs a compile-time 24-iteration unrolled loop + predicated tail,
// block reduces, writes its 4 partials directly (no atomics).
#define EBODY(pp, gg, ll)                                   \
    do {                                                    \
        np += pp.x + pp.y + pp.z + pp.w;                    \
        ng += gg.x + gg.y + gg.z + gg.w;                    \
        float e0 = __expf(ll.x - M), e1 = __expf(ll.y - M); \
        float e2 = __expf(ll.z - M), e3 = __expf(ll.w - M); \
        s  = fmaf((float)pp.x, e0, s);                      \
        s  = fmaf((float)pp.y, e1, s);                      \
        s  = fmaf((float)pp.z, e2, s);                      \
        s  = fmaf((float)pp.w, e3, s);                      \
        sg = fmaf((float)gg.x, ll.x, sg);                   \
        sg = fmaf((float)gg.y, ll.y, sg);                   \
        sg = fmaf((float)gg.z, ll.z, sg);                   \
        sg = fmaf((float)gg.w, ll.w, sg);                   \
    } while (0)

__global__ __launch_bounds__(256) void event_kernel(
        const int* __restrict__ pass, const int* __restrict__ good,
        const int* __restrict__ qidx, const float* __restrict__ lg,
        const unsigned* __restrict__ mq, float* __restrict__ acc) {
    int t   = blockIdx.x >> 1;
    int h   = blockIdx.x & 1;
    int tid = threadIdx.x;
    int q = qidx[t] & 1;
    float M = finv(mq[q]);
    const float4* lrow = (const float4*)(lg + (size_t)q * N_CL) + (size_t)h * ECHUNK;
    const int4*   prow = (const int4*)(pass + (size_t)t * N_CL) + (size_t)h * ECHUNK;
    const int4*   grow = (const int4*)(good + (size_t)t * N_CL) + (size_t)h * ECHUNK;

    float s = 0.f, sg = 0.f;
    int np = 0, ng = 0;
    #pragma unroll 4
    for (int it = 0; it < EFULL; ++it) {
        int i = it * 256 + tid;
        int4   p = prow[i];
        int4   g = grow[i];
        float4 l = lrow[i];
        EBODY(p, g, l);
    }
    {
        int i = EFULL * 256 + tid;
        if (i < ECHUNK) {
            int4   p = prow[i];
            int4   g = grow[i];
            float4 l = lrow[i];
            EBODY(p, g, l);
        }
    }

    // wave reduce (64 lanes)
    for (int off = 32; off; off >>= 1) {
        s  += __shfl_xor(s, off);
        sg += __shfl_xor(sg, off);
        np += __shfl_xor(np, off);
        ng += __shfl_xor(ng, off);
    }
    __shared__ float rs[4], rsg[4];
    __shared__ int   rnp[4], rng[4];
    int w = tid >> 6;
    if ((tid & 63) == 0) { rs[w] = s; rsg[w] = sg; rnp[w] = np; rng[w] = ng; }
    __syncthreads();
    if (tid == 0) {
        s  = rs[0] + rs[1] + rs[2] + rs[3];
        sg = rsg[0] + rsg[1] + rsg[2] + rsg[3];
        np = rnp[0] + rnp[1] + rnp[2] + rnp[3];
        ng = rng[0] + rng[1] + rng[2] + rng[3];
        float* a = acc + (size_t)blockIdx.x * 4;
        a[0] = s; a[1] = sg; a[2] = (float)np; a[3] = (float)ng;
    }
}

// ---------------------------------------------------------------- kernel E
// Combine halves, scan valid flags, apply discount, reduce to scalar loss.
__global__ __launch_bounds__(1024) void final_kernel(
        const int* __restrict__ qidx, const float* __restrict__ acc,
        const unsigned* __restrict__ mq, float* __restrict__ out) {
    int t = threadIdx.x;
    float s = 0.f, sg = 0.f, np = 0.f, ng = 0.f;
    int q = 0;
    if (t < T_SEL) {
        const float* a = acc + (size_t)t * 8;
        s  = a[0] + a[4];
        sg = a[1] + a[5];
        np = a[2] + a[6];
        ng = a[3] + a[7];
        q = qidx[t] & 1;
    }
    float M  = finv(mq[q]);
    float nb = np - ng;
    int valid = (t < T_SEL) && (ng > 0.5f) && (nb > 0.5f);

    __shared__ int sc[1024];
    sc[t] = valid;
    __syncthreads();
    for (int off = 1; off < 1024; off <<= 1) {
        int v = (t >= off) ? sc[t - off] : 0;
        __syncthreads();
        sc[t] += v;
        __syncthreads();
    }
    int sb    = sc[t] - valid;          // exclusive scan
    int steps = sc[1023];               // total valid count

    float ce   = logf(s) + M - sg / fmaxf(ng, 1.0f);
    float wgt  = powf(0.995f, (float)sb) * nb / fmaxf(np, 1.0f);
    float term = valid ? wgt * ce : 0.0f;

    __shared__ float sf[1024];
    sf[t] = term;
    __syncthreads();
    for (int off = 512; off; off >>= 1) {
        if (t < off) sf[t] += sf[t + off];
        __syncthreads();
    }
    if (t == 0) out[0] = sf[0] / fmaxf((float)steps, 1.0f);
}

extern "C" void kernel_launch(void* const* d_in, const int* in_sizes, int n_in,
                              void* d_out, int out_size, void* d_ws, size_t ws_size,
                              hipStream_t stream) {
    const float* X     = (const float*)d_in[0];
    const float* W1    = (const float*)d_in[1];
    const float* b1    = (const float*)d_in[2];
    const float* W2    = (const float*)d_in[3];
    const float* b2    = (const float*)d_in[4];
    const float* keysW = (const float*)d_in[5];
    const int*   pass  = (const int*)d_in[6];   // bool -> int32, one per clause
    const int*   good  = (const int*)d_in[7];
    const int*   qidx  = (const int*)d_in[8];

    float*    ws  = (float*)d_ws;
    float*    wk  = ws + WK_OFF;
    float*    ck  = ws + CK_OFF;
    unsigned* mq  = (unsigned*)(ws + MQ_OFF);
    float*    lg  = ws + LG_OFF;
    float*    acc = ws + ACC_OFF;
    float*    out = (float*)d_out;

    hipLaunchKernelGGL(prep_kernel, dim3(1), dim3(256), 0, stream,
                       W2, b2, keysW, wk, ck, mq);
    hipLaunchKernelGGL(mlp_kernel, dim3(NBLK), dim3(256), 0, stream,
                       X, W1, b1, wk, ck, lg, mq);
    hipLaunchKernelGGL(event_kernel, dim3(T_SEL * 2), dim3(256), 0, stream,
                       pass, good, qidx, lg, mq, acc);
    hipLaunchKernelGGL(final_kernel, dim3(1), dim3(1024), 0, stream,
                       qidx, acc, mq, out);
}

// Round 4
// 146.068 us; speedup vs baseline: 1.8744x; 1.8744x over previous
//
#include <hip/hip_runtime.h>
#include <hip/hip_bf16.h>

#define N_CL   50000
#define FEAT   64
#define HID    256
#define KD     256
#define T_SEL  1000
#define NBLK   782                 // ceil(50000/64) clause groups
#define JSPLIT 4                   // hidden-quarter blocks per clause group
#define ECHUNK 6250                // int4s per half-event (N_CL/4/2)
#define EFULL  24                  // full 256-wide iterations (24*256=6144)

// ws layout (in floats)
#define WK_OFF  0                          // 256*2 folded weights
#define CK_OFF  512                        // 2 bias constants
#define MQ_OFF  514                        // 2 uint max-keys
#define P_OFF   520                        // JSPLIT*2*N_CL partial logits
#define LG_OFF  (P_OFF + JSPLIT * 2 * N_CL)   // 2*N_CL final logits
#define ACC_OFF (LG_OFF + 2 * N_CL)        // T_SEL*8: per (t,half) s,sg,np,ng

__device__ __forceinline__ unsigned fkey(float f) {
    unsigned u = __float_as_uint(f);
    return (u & 0x80000000u) ? ~u : (u | 0x80000000u);   // monotone float->uint
}
__device__ __forceinline__ float finv(unsigned k) {
    unsigned u = (k & 0x80000000u) ? (k ^ 0x80000000u) : ~k;
    return __uint_as_float(u);
}

// ---------------------------------------------------------------- kernel A
// Wk[j][q] = dot(W2 row j, keys_W row q); ck[q] = dot(keys_W[q], b2).
__global__ __launch_bounds__(256) void prep_kernel(
        const float* __restrict__ W2, const float* __restrict__ b2,
        const float* __restrict__ keysW,
        float* __restrict__ wk, float* __restrict__ ck,
        unsigned* __restrict__ mq) {
    __shared__ float sk0[KD], sk1[KD], sb2[KD], red[256];
    int tid = threadIdx.x;
    sk0[tid] = keysW[tid];
    sk1[tid] = keysW[KD + tid];
    sb2[tid] = b2[tid];
    if (tid < 2) mq[tid] = 0u;
    __syncthreads();

    const float* w2r = W2 + (size_t)tid * KD;
    float a0 = 0.f, a1 = 0.f;
    #pragma unroll 4
    for (int k = 0; k < KD; k++) {
        float w = w2r[k];
        a0 = fmaf(w, sk0[k], a0);
        a1 = fmaf(w, sk1[k], a1);
    }
    wk[tid * 2 + 0] = a0;
    wk[tid * 2 + 1] = a1;

    red[tid] = sk0[tid] * sb2[tid];
    __syncthreads();
    for (int s = 128; s > 0; s >>= 1) { if (tid < s) red[tid] += red[tid + s]; __syncthreads(); }
    if (tid == 0) ck[0] = red[0];
    __syncthreads();
    red[tid] = sk1[tid] * sb2[tid];
    __syncthreads();
    for (int s = 128; s > 0; s >>= 1) { if (tid < s) red[tid] += red[tid + s]; __syncthreads(); }
    if (tid == 0) ck[1] = red[0];
}

// ---------------------------------------------------------------- kernel B
// MLP partial logits: block = (clause group nb, hidden quarter p).
// k-loop is FULLY unrolled so x[] is compile-time indexed -> stays in VGPRs
// (partial unroll made x[] runtime-indexed -> scratch spill, the round-3 bug).
// W1/b1/wk addresses are wave-uniform -> scalar loads.
__global__ __launch_bounds__(64, 2) void mlp_kernel(
        const float* __restrict__ X, const float* __restrict__ W1,
        const float* __restrict__ b1, const float* __restrict__ wk,
        float* __restrict__ P) {
    int nb = blockIdx.x >> 2;       // p adjacent: 4 blocks sharing X rows
    int p  = blockIdx.x & 3;        // dispatch together -> X L2/L3-hot
    int n  = nb * 64 + threadIdx.x;
    int nc = (n < N_CL) ? n : (N_CL - 1);

    float x[FEAT];
    const float4* xp = (const float4*)(X + (size_t)nc * FEAT);
    #pragma unroll
    for (int k4 = 0; k4 < FEAT / 4; k4++) {
        float4 v = xp[k4];
        x[4 * k4 + 0] = v.x; x[4 * k4 + 1] = v.y;
        x[4 * k4 + 2] = v.z; x[4 * k4 + 3] = v.w;
    }

    float l0 = 0.f, l1 = 0.f;
    int j0 = p * 64;
    for (int jg = 0; jg < 64; jg += 16) {   // runtime loop: h indexed by u only
        float h[16];
        #pragma unroll
        for (int u = 0; u < 16; u++) h[u] = b1[j0 + jg + u];
        #pragma unroll
        for (int k = 0; k < FEAT; k++) {    // FULL unroll: x[k] static
            const float* w1r = W1 + (size_t)k * HID + j0 + jg;
            float xv = x[k];
            #pragma unroll
            for (int u = 0; u < 16; u++) h[u] = fmaf(xv, w1r[u], h[u]);
        }
        #pragma unroll
        for (int u = 0; u < 16; u++) {
            float hv = fmaxf(h[u], 0.0f);
            l0 = fmaf(hv, wk[(j0 + jg + u) * 2 + 0], l0);
            l1 = fmaf(hv, wk[(j0 + jg + u) * 2 + 1], l1);
        }
    }
    if (n < N_CL) {
        P[((size_t)p * 2 + 0) * N_CL + n] = l0;
        P[((size_t)p * 2 + 1) * N_CL + n] = l1;
    }
}

// ---------------------------------------------------------------- kernel C
// Sum the JSPLIT partials, add ck, write final logits, atomicMax row maxes.
__global__ __launch_bounds__(256) void logits_fin(
        const float* __restrict__ P, const float* __restrict__ ck,
        float* __restrict__ lg, unsigned* __restrict__ mq) {
    int n = blockIdx.x * 256 + threadIdx.x;
    float m0 = -1e30f, m1 = -1e30f;
    if (n < N_CL) {
        float l0 = ck[0], l1 = ck[1];
        #pragma unroll
        for (int p = 0; p < JSPLIT; p++) {
            l0 += P[((size_t)p * 2 + 0) * N_CL + n];
            l1 += P[((size_t)p * 2 + 1) * N_CL + n];
        }
        lg[n]        = l0;
        lg[N_CL + n] = l1;
        m0 = l0; m1 = l1;
    }
    for (int off = 32; off; off >>= 1) {
        m0 = fmaxf(m0, __shfl_xor(m0, off));
        m1 = fmaxf(m1, __shfl_xor(m1, off));
    }
    __shared__ float sm0[4], sm1[4];
    int w = threadIdx.x >> 6;
    if ((threadIdx.x & 63) == 0) { sm0[w] = m0; sm1[w] = m1; }
    __syncthreads();
    if (threadIdx.x == 0) {
        m0 = fmaxf(fmaxf(sm0[0], sm0[1]), fmaxf(sm0[2], sm0[3]));
        m1 = fmaxf(fmaxf(sm1[0], sm1[1]), fmaxf(sm1[2], sm1[3]));
        atomicMax(mq + 0, fkey(m0));
        atomicMax(mq + 1, fkey(m1));
    }
}

// ---------------------------------------------------------------- kernel D
// Streaming pass over the int32 masks. Grid = T_SEL*2 (event x half); each
// thread runs a compile-time 24-iteration unrolled loop + predicated tail,
// block reduces, writes its 4 partials directly (no atomics).
#define EBODY(pp, gg, ll)                                   \
    do {                                                    \
        np += pp.x + pp.y + pp.z + pp.w;                    \
        ng += gg.x + gg.y + gg.z + gg.w;                    \
        float e0 = __expf(ll.x - M), e1 = __expf(ll.y - M); \
        float e2 = __expf(ll.z - M), e3 = __expf(ll.w - M); \
        s  = fmaf((float)pp.x, e0, s);                      \
        s  = fmaf((float)pp.y, e1, s);                      \
        s  = fmaf((float)pp.z, e2, s);                      \
        s  = fmaf((float)pp.w, e3, s);                      \
        sg = fmaf((float)gg.x, ll.x, sg);                   \
        sg = fmaf((float)gg.y, ll.y, sg);                   \
        sg = fmaf((float)gg.z, ll.z, sg);                   \
        sg = fmaf((float)gg.w, ll.w, sg);                   \
    } while (0)

__global__ __launch_bounds__(256) void event_kernel(
        const int* __restrict__ pass, const int* __restrict__ good,
        const int* __restrict__ qidx, const float* __restrict__ lg,
        const unsigned* __restrict__ mq, float* __restrict__ acc) {
    int t   = blockIdx.x >> 1;
    int h   = blockIdx.x & 1;
    int tid = threadIdx.x;
    int q = qidx[t] & 1;
    float M = finv(mq[q]);
    const float4* lrow = (const float4*)(lg + (size_t)q * N_CL) + (size_t)h * ECHUNK;
    const int4*   prow = (const int4*)(pass + (size_t)t * N_CL) + (size_t)h * ECHUNK;
    const int4*   grow = (const int4*)(good + (size_t)t * N_CL) + (size_t)h * ECHUNK;

    float s = 0.f, sg = 0.f;
    int np = 0, ng = 0;
    #pragma unroll 4
    for (int it = 0; it < EFULL; ++it) {
        int i = it * 256 + tid;
        int4   p = prow[i];
        int4   g = grow[i];
        float4 l = lrow[i];
        EBODY(p, g, l);
    }
    {
        int i = EFULL * 256 + tid;
        if (i < ECHUNK) {
            int4   p = prow[i];
            int4   g = grow[i];
            float4 l = lrow[i];
            EBODY(p, g, l);
        }
    }

    // wave reduce (64 lanes)
    for (int off = 32; off; off >>= 1) {
        s  += __shfl_xor(s, off);
        sg += __shfl_xor(sg, off);
        np += __shfl_xor(np, off);
        ng += __shfl_xor(ng, off);
    }
    __shared__ float rs[4], rsg[4];
    __shared__ int   rnp[4], rng[4];
    int w = tid >> 6;
    if ((tid & 63) == 0) { rs[w] = s; rsg[w] = sg; rnp[w] = np; rng[w] = ng; }
    __syncthreads();
    if (tid == 0) {
        s  = rs[0] + rs[1] + rs[2] + rs[3];
        sg = rsg[0] + rsg[1] + rsg[2] + rsg[3];
        np = rnp[0] + rnp[1] + rnp[2] + rnp[3];
        ng = rng[0] + rng[1] + rng[2] + rng[3];
        float* a = acc + (size_t)blockIdx.x * 4;
        a[0] = s; a[1] = sg; a[2] = (float)np; a[3] = (float)ng;
    }
}

// ---------------------------------------------------------------- kernel E
// Combine halves, scan valid flags, apply discount, reduce to scalar loss.
__global__ __launch_bounds__(1024) void final_kernel(
        const int* __restrict__ qidx, const float* __restrict__ acc,
        const unsigned* __restrict__ mq, float* __restrict__ out) {
    int t = threadIdx.x;
    float s = 0.f, sg = 0.f, np = 0.f, ng = 0.f;
    int q = 0;
    if (t < T_SEL) {
        const float* a = acc + (size_t)t * 8;
        s  = a[0] + a[4];
        sg = a[1] + a[5];
        np = a[2] + a[6];
        ng = a[3] + a[7];
        q = qidx[t] & 1;
    }
    float M  = finv(mq[q]);
    float nb = np - ng;
    int valid = (t < T_SEL) && (ng > 0.5f) && (nb > 0.5f);

    __shared__ int sc[1024];
    sc[t] = valid;
    __syncthreads();
    for (int off = 1; off < 1024; off <<= 1) {
        int v = (t >= off) ? sc[t - off] : 0;
        __syncthreads();
        sc[t] += v;
        __syncthreads();
    }
    int sb    = sc[t] - valid;          // exclusive scan
    int steps = sc[1023];               // total valid count

    float ce   = logf(s) + M - sg / fmaxf(ng, 1.0f);
    float wgt  = powf(0.995f, (float)sb) * nb / fmaxf(np, 1.0f);
    float term = valid ? wgt * ce : 0.0f;

    __shared__ float sf[1024];
    sf[t] = term;
    __syncthreads();
    for (int off = 512; off; off >>= 1) {
        if (t < off) sf[t] += sf[t + off];
        __syncthreads();
    }
    if (t == 0) out[0] = sf[0] / fmaxf((float)steps, 1.0f);
}

extern "C" void kernel_launch(void* const* d_in, const int* in_sizes, int n_in,
                              void* d_out, int out_size, void* d_ws, size_t ws_size,
                              hipStream_t stream) {
    const float* X     = (const float*)d_in[0];
    const float* W1    = (const float*)d_in[1];
    const float* b1    = (const float*)d_in[2];
    const float* W2    = (const float*)d_in[3];
    const float* b2    = (const float*)d_in[4];
    const float* keysW = (const float*)d_in[5];
    const int*   pass  = (const int*)d_in[6];   // bool -> int32, one per clause
    const int*   good  = (const int*)d_in[7];
    const int*   qidx  = (const int*)d_in[8];

    float*    ws  = (float*)d_ws;
    float*    wk  = ws + WK_OFF;
    float*    ck  = ws + CK_OFF;
    unsigned* mq  = (unsigned*)(ws + MQ_OFF);
    float*    P   = ws + P_OFF;
    float*    lg  = ws + LG_OFF;
    float*    acc = ws + ACC_OFF;
    float*    out = (float*)d_out;

    hipLaunchKernelGGL(prep_kernel, dim3(1), dim3(256), 0, stream,
                       W2, b2, keysW, wk, ck, mq);
    hipLaunchKernelGGL(mlp_kernel, dim3(NBLK * JSPLIT), dim3(64), 0, stream,
                       X, W1, b1, wk, P);
    hipLaunchKernelGGL(logits_fin, dim3((N_CL + 255) / 256), dim3(256), 0, stream,
                       P, ck, lg, mq);
    hipLaunchKernelGGL(event_kernel, dim3(T_SEL * 2), dim3(256), 0, stream,
                       pass, good, qidx, lg, mq, acc);
    hipLaunchKernelGGL(final_kernel, dim3(1), dim3(1024), 0, stream,
                       qidx, acc, mq, out);
}